// Round 4
// baseline (231.980 us; speedup 1.0000x reference)
//
#include <hip/hip_runtime.h>
#include <hip/hip_fp16.h>
#include <math.h>

#define D 128
#define LN_EPS 1e-5f
#define BKT 64   // slots per destination; deg ~ Poisson(10), P(deg>64) ~ 1e-30

typedef _Float16 f16x8 __attribute__((ext_vector_type(8)));
typedef float    f32x4 __attribute__((ext_vector_type(4)));

// ---------------- prep: W^T -> fp16 (once, 32 KB) + zero degi ----------------
__global__ void prep_kernel(const float* __restrict__ W, _Float16* __restrict__ wtg,
                            int* __restrict__ degi, int N) {
    int idx = blockIdx.x * 256 + threadIdx.x;     // [0, 16384)
    int k = idx >> 7;
    int n = idx & 127;
    wtg[n * D + k] = (_Float16)W[k * D + n];
    for (int i = idx; i < N; i += 64 * 256) degi[i] = 0;
}

// ---------------- fused gemm || bucket (round-0 exact) ----------------
__global__ void fused_kernel(const float* __restrict__ x, const _Float16* __restrict__ wtg,
                             unsigned* __restrict__ h2,
                             const int* __restrict__ src, const int* __restrict__ dst,
                             int* __restrict__ degi, int* __restrict__ bucket,
                             int N, int E, int nbG) {
    __shared__ _Float16 xs[64][136];
    int tid = threadIdx.x;

    if ((int)blockIdx.x >= nbG) {
        int e = (blockIdx.x - nbG) * 256 + tid;
        if (e < E) {
            int d = dst[e];
            int p = atomicAdd(&degi[d], 1);
            if (p < BKT) bucket[(size_t)d * BKT + p] = src[e];
        }
        return;
    }

    int row0 = blockIdx.x * 64;
#pragma unroll
    for (int i = 0; i < 8; ++i) {
        int idx = i * 256 + tid;
        int r   = idx >> 5;
        int c4  = idx & 31;
        float4 v = make_float4(0.f, 0.f, 0.f, 0.f);
        if (row0 + r < N) v = *(const float4*)&x[(size_t)(row0 + r) * D + c4 * 4];
        __half2 lo = __floats2half2_rn(v.x, v.y);
        __half2 hi = __floats2half2_rn(v.z, v.w);
        *(__half2*)&xs[r][c4 * 4]     = lo;
        *(__half2*)&xs[r][c4 * 4 + 2] = hi;
    }
    __syncthreads();

    int l     = tid & 63;
    int mtile = tid >> 6;
    int mn    = l & 15;
    int kq    = (l >> 4) * 8;
    f32x4 acc[8];
#pragma unroll
    for (int nt = 0; nt < 8; ++nt) acc[nt] = (f32x4){0.f, 0.f, 0.f, 0.f};

#pragma unroll
    for (int ks = 0; ks < 4; ++ks) {
        int kb = ks * 32 + kq;
        f16x8 a = *(f16x8*)&xs[mtile * 16 + mn][kb];
#pragma unroll
        for (int nt = 0; nt < 8; ++nt) {
            f16x8 bf = *(const f16x8*)&wtg[(nt * 16 + mn) * D + kb];
            acc[nt] = __builtin_amdgcn_mfma_f32_16x16x32_f16(a, bf, acc[nt], 0, 0, 0);
        }
    }

    int quad = l >> 4;
#pragma unroll
    for (int nt = 0; nt < 8; ++nt) {
#pragma unroll
        for (int rg = 0; rg < 4; ++rg) {
            float v  = acc[nt][rg];
            float pv = __shfl_xor(v, 1);
            if (!(l & 1)) {
                int row = row0 + mtile * 16 + quad * 4 + rg;
                if (row < N) {
                    __half2 p = __floats2half2_rn(v, pv);
                    h2[(size_t)row * (D / 2) + nt * 8 + (mn >> 1)] = *(unsigned*)&p;
                }
            }
        }
    }
}

// ---------------- standalone GEMM replica (idempotent: rewrites identical h2) ----------------
// MEASUREMENT: dispatched 4 extra times; gemm_warm = (dur - 143.5us) / 4.
__global__ void gemm_kernel(const float* __restrict__ x, const _Float16* __restrict__ wtg,
                            unsigned* __restrict__ h2, int N) {
    __shared__ _Float16 xs[64][136];
    int tid = threadIdx.x;

    int row0 = blockIdx.x * 64;
#pragma unroll
    for (int i = 0; i < 8; ++i) {
        int idx = i * 256 + tid;
        int r   = idx >> 5;
        int c4  = idx & 31;
        float4 v = make_float4(0.f, 0.f, 0.f, 0.f);
        if (row0 + r < N) v = *(const float4*)&x[(size_t)(row0 + r) * D + c4 * 4];
        __half2 lo = __floats2half2_rn(v.x, v.y);
        __half2 hi = __floats2half2_rn(v.z, v.w);
        *(__half2*)&xs[r][c4 * 4]     = lo;
        *(__half2*)&xs[r][c4 * 4 + 2] = hi;
    }
    __syncthreads();

    int l     = tid & 63;
    int mtile = tid >> 6;
    int mn    = l & 15;
    int kq    = (l >> 4) * 8;
    f32x4 acc[8];
#pragma unroll
    for (int nt = 0; nt < 8; ++nt) acc[nt] = (f32x4){0.f, 0.f, 0.f, 0.f};

#pragma unroll
    for (int ks = 0; ks < 4; ++ks) {
        int kb = ks * 32 + kq;
        f16x8 a = *(f16x8*)&xs[mtile * 16 + mn][kb];
#pragma unroll
        for (int nt = 0; nt < 8; ++nt) {
            f16x8 bf = *(const f16x8*)&wtg[(nt * 16 + mn) * D + kb];
            acc[nt] = __builtin_amdgcn_mfma_f32_16x16x32_f16(a, bf, acc[nt], 0, 0, 0);
        }
    }

    int quad = l >> 4;
#pragma unroll
    for (int nt = 0; nt < 8; ++nt) {
#pragma unroll
        for (int rg = 0; rg < 4; ++rg) {
            float v  = acc[nt][rg];
            float pv = __shfl_xor(v, 1);
            if (!(l & 1)) {
                int row = row0 + mtile * 16 + quad * 4 + rg;
                if (row < N) {
                    __half2 p = __floats2half2_rn(v, pv);
                    h2[(size_t)row * (D / 2) + nt * 8 + (mn >> 1)] = *(unsigned*)&p;
                }
            }
        }
    }
}

// ---------------- fused pull-aggregate + bias + LayerNorm + ReLU ----------------
__device__ __forceinline__ void acc_edge(float& a0, float& a1, unsigned u, float w) {
    __half2 hv = *(__half2*)&u;
    a0 = fmaf(__low2float(hv),  w, a0);
    a1 = fmaf(__high2float(hv), w, a1);
}

__global__ void gather_ln_kernel(const int* __restrict__ bucket, const int* __restrict__ degi,
                                 const unsigned* __restrict__ h2, const float* __restrict__ b,
                                 const float* __restrict__ g, const float* __restrict__ be,
                                 float* __restrict__ out, int N) {
    int row  = blockIdx.x * 4 + (threadIdx.x >> 6);
    int lane = threadIdx.x & 63;
    if (row >= N) return;
    int dg   = degi[row];
    int dgc  = dg < BKT ? dg : BKT;
    float di = rsqrtf((float)dg + 1.0f);
    float sw = di * di;
    unsigned su = h2[(size_t)row * (D / 2) + lane];        // self-loop
    float acc0 = 0.f, acc1 = 0.f;
    acc_edge(acc0, acc1, su, sw);
    const int* bk = bucket + (size_t)row * BKT;

    int e = 0;
    for (; e + 8 <= dgc; e += 8) {
        int4 ra = *(const int4*)&bk[e];
        int4 rb = *(const int4*)&bk[e + 4];
        int s[8] = {ra.x, ra.y, ra.z, ra.w, rb.x, rb.y, rb.z, rb.w};
        unsigned u[8]; float wgt[8];
#pragma unroll
        for (int j = 0; j < 8; ++j) u[j] = h2[(size_t)s[j] * (D / 2) + lane];
#pragma unroll
        for (int j = 0; j < 8; ++j) wgt[j] = rsqrtf((float)degi[s[j]] + 1.0f) * di;
#pragma unroll
        for (int j = 0; j < 8; ++j) acc_edge(acc0, acc1, u[j], wgt[j]);
    }
    int rem = dgc - e;
    if (rem & 4) {
        int4 ra = *(const int4*)&bk[e];
        int s[4] = {ra.x, ra.y, ra.z, ra.w};
        unsigned u[4]; float wgt[4];
#pragma unroll
        for (int j = 0; j < 4; ++j) u[j] = h2[(size_t)s[j] * (D / 2) + lane];
#pragma unroll
        for (int j = 0; j < 4; ++j) wgt[j] = rsqrtf((float)degi[s[j]] + 1.0f) * di;
#pragma unroll
        for (int j = 0; j < 4; ++j) acc_edge(acc0, acc1, u[j], wgt[j]);
        e += 4;
    }
    if (rem & 2) {
        int s0 = bk[e], s1 = bk[e + 1];
        unsigned u0 = h2[(size_t)s0 * (D / 2) + lane];
        unsigned u1 = h2[(size_t)s1 * (D / 2) + lane];
        float w0 = rsqrtf((float)degi[s0] + 1.0f) * di;
        float w1 = rsqrtf((float)degi[s1] + 1.0f) * di;
        acc_edge(acc0, acc1, u0, w0);
        acc_edge(acc0, acc1, u1, w1);
        e += 2;
    }
    if (rem & 1) {
        int s0 = bk[e];
        unsigned u0 = h2[(size_t)s0 * (D / 2) + lane];
        float w0 = rsqrtf((float)degi[s0] + 1.0f) * di;
        acc_edge(acc0, acc1, u0, w0);
    }

    float2 bb = *(const float2*)&b[lane * 2];
    float v0 = acc0 + bb.x;
    float v1 = acc1 + bb.y;
    float s = v0 + v1;
    float q = v0 * v0 + v1 * v1;
#pragma unroll
    for (int off = 32; off; off >>= 1) {
        s += __shfl_xor(s, off);
        q += __shfl_xor(q, off);
    }
    float mean = s * (1.0f / 128.0f);
    float var  = q * (1.0f / 128.0f) - mean * mean;
    float rstd = rsqrtf(var + LN_EPS);
    float2 gg = *(const float2*)&g[lane * 2];
    float2 eb = *(const float2*)&be[lane * 2];
    float y0 = (v0 - mean) * rstd * gg.x + eb.x;
    float y1 = (v1 - mean) * rstd * gg.y + eb.y;
    *(float2*)&out[(size_t)row * D + lane * 2] = make_float2(fmaxf(y0, 0.0f), fmaxf(y1, 0.0f));
}

extern "C" void kernel_launch(void* const* d_in, const int* in_sizes, int n_in,
                              void* d_out, int out_size, void* d_ws, size_t ws_size,
                              hipStream_t stream) {
    const float* x  = (const float*)d_in[0];
    const int*   ei = (const int*)d_in[1];
    const float* W  = (const float*)d_in[2];
    const float* b  = (const float*)d_in[3];
    const float* g  = (const float*)d_in[4];
    const float* be = (const float*)d_in[5];

    int N = in_sizes[0] / D;
    int E = in_sizes[1] / 2;
    const int* src = ei;
    const int* dst = ei + E;

    float* out = (float*)d_out;

    char* w = (char*)d_ws;
    unsigned* h2    = (unsigned*)w;           w += (size_t)N * (D / 2) * sizeof(unsigned);
    int*      degi  = (int*)w;                w += (size_t)N * sizeof(int);
    _Float16* wtg   = (_Float16*)w;           w += (size_t)D * D * sizeof(_Float16);
    int*      bucket= (int*)w;                w += (size_t)N * BKT * sizeof(int);

    int nbG = (N + 63) / 64;
    int nbB = (E + 255) / 256;

    prep_kernel <<<64,        256, 0, stream>>>(W, wtg, degi, N);
    fused_kernel<<<nbG + nbB, 256, 0, stream>>>(x, wtg, h2, src, dst, degi, bucket,
                                                N, E, nbG);
    // MEASUREMENT ROUND: 4 idempotent GEMM replays attribute the 45us fused cost.
    // gemm_warm = (dur - 143.5) / 4. GEMM-dominant -> ~320-340us; bucket-dominant
    // -> ~180-205us.
    for (int rep = 0; rep < 4; ++rep) {
        gemm_kernel<<<nbG, 256, 0, stream>>>(x, wtg, h2, N);
    }
    gather_ln_kernel<<<(N + 3) / 4, 256, 0, stream>>>(bucket, degi, h2,
                                                      b, g, be, out, N);
}

// Round 6
// 157.882 us; speedup vs baseline: 1.4693x; 1.4693x over previous
//
#include <hip/hip_runtime.h>
#include <hip/hip_fp16.h>
#include <math.h>

#define D 128
#define LN_EPS 1e-5f
#define BKT 64   // slots per destination; deg ~ Poisson(10), P(deg>64) ~ 1e-30

typedef _Float16 f16x8 __attribute__((ext_vector_type(8)));
typedef float    f32x4 __attribute__((ext_vector_type(4)));

// ---------------- prep: W^T -> fp16 (once, 32 KB) + zero degi ----------------
__global__ void prep_kernel(const float* __restrict__ W, _Float16* __restrict__ wtg,
                            int* __restrict__ degi, int N) {
    int idx = blockIdx.x * 256 + threadIdx.x;     // [0, 16384)
    int k = idx >> 7;
    int n = idx & 127;
    wtg[n * D + k] = (_Float16)W[k * D + n];
    for (int i = idx; i < N; i += 64 * 256) degi[i] = 0;
}

// ---------------- fused gemm || bucket: one dispatch ----------------
// GEMM half rewritten LDS-free: each lane loads its MFMA A-fragment directly from
// global (coalesced 128B/row segments), converts fp32->fp16 in-register. No LDS,
// no __syncthreads -> waves fully independent, loads pipelined across k-steps.
// (Round-4 replay showed gemm=22us vs ~6us BW floor; barrier-serialized staging
// with ~3 blocks/CU was the mechanism. Bucket half unchanged: round-0 exact.)
__global__ void fused_kernel(const float* __restrict__ x, const _Float16* __restrict__ wtg,
                             unsigned* __restrict__ h2,
                             const int* __restrict__ src, const int* __restrict__ dst,
                             int* __restrict__ degi, int* __restrict__ bucket,
                             int N, int E, int nbG) {
    int tid = threadIdx.x;

    if ((int)blockIdx.x >= nbG) {
        int e = (blockIdx.x - nbG) * 256 + tid;
        if (e < E) {
            int d = dst[e];
            int p = atomicAdd(&degi[d], 1);
            if (p < BKT) bucket[(size_t)d * BKT + p] = src[e];
        }
        return;
    }

    int row0  = blockIdx.x * 64;
    int l     = tid & 63;
    int mtile = tid >> 6;
    int mn    = l & 15;
    int quad  = l >> 4;                 // 0..3
    int xrow  = row0 + mtile * 16 + mn;
    bool rok  = xrow < N;

    // A fragments: 4 k-steps x 8 fp32 -> f16x8, loaded directly from global.
    // Lane (mn, quad): row xrow, cols [ks*32 + quad*8, +8). All 8 loads independent.
    f16x8 afrag[4];
#pragma unroll
    for (int ks = 0; ks < 4; ++ks) {
        int kb = ks * 32 + quad * 8;
        float4 v0 = make_float4(0.f, 0.f, 0.f, 0.f);
        float4 v1 = v0;
        if (rok) {
            v0 = *(const float4*)&x[(size_t)xrow * D + kb];
            v1 = *(const float4*)&x[(size_t)xrow * D + kb + 4];
        }
        f16x8 a;
        a[0] = (_Float16)v0.x; a[1] = (_Float16)v0.y;
        a[2] = (_Float16)v0.z; a[3] = (_Float16)v0.w;
        a[4] = (_Float16)v1.x; a[5] = (_Float16)v1.y;
        a[6] = (_Float16)v1.z; a[7] = (_Float16)v1.w;
        afrag[ks] = a;
    }

    f32x4 acc[8];
#pragma unroll
    for (int nt = 0; nt < 8; ++nt) acc[nt] = (f32x4){0.f, 0.f, 0.f, 0.f};

#pragma unroll
    for (int ks = 0; ks < 4; ++ks) {
        int kb = ks * 32 + quad * 8;
#pragma unroll
        for (int nt = 0; nt < 8; ++nt) {
            f16x8 bf = *(const f16x8*)&wtg[(nt * 16 + mn) * D + kb];
            acc[nt] = __builtin_amdgcn_mfma_f32_16x16x32_f16(afrag[ks], bf, acc[nt], 0, 0, 0);
        }
    }

#pragma unroll
    for (int nt = 0; nt < 8; ++nt) {
#pragma unroll
        for (int rg = 0; rg < 4; ++rg) {
            float v  = acc[nt][rg];
            float pv = __shfl_xor(v, 1);
            if (!(l & 1)) {
                int row = row0 + mtile * 16 + quad * 4 + rg;
                if (row < N) {
                    __half2 p = __floats2half2_rn(v, pv);
                    h2[(size_t)row * (D / 2) + nt * 8 + (mn >> 1)] = *(unsigned*)&p;
                }
            }
        }
    }
}

// ---------------- fused pull-aggregate + bias + LayerNorm + ReLU ----------------
__device__ __forceinline__ void acc_edge(float& a0, float& a1, unsigned u, float w) {
    __half2 hv = *(__half2*)&u;
    a0 = fmaf(__low2float(hv),  w, a0);
    a1 = fmaf(__high2float(hv), w, a1);
}

__global__ void gather_ln_kernel(const int* __restrict__ bucket, const int* __restrict__ degi,
                                 const unsigned* __restrict__ h2, const float* __restrict__ b,
                                 const float* __restrict__ g, const float* __restrict__ be,
                                 float* __restrict__ out, int N) {
    int row  = blockIdx.x * 4 + (threadIdx.x >> 6);
    int lane = threadIdx.x & 63;
    if (row >= N) return;
    int dg   = degi[row];
    int dgc  = dg < BKT ? dg : BKT;
    float di = rsqrtf((float)dg + 1.0f);
    float sw = di * di;
    unsigned su = h2[(size_t)row * (D / 2) + lane];        // self-loop
    float acc0 = 0.f, acc1 = 0.f;
    acc_edge(acc0, acc1, su, sw);
    const int* bk = bucket + (size_t)row * BKT;

    int e = 0;
    for (; e + 8 <= dgc; e += 8) {
        int4 ra = *(const int4*)&bk[e];
        int4 rb = *(const int4*)&bk[e + 4];
        int s[8] = {ra.x, ra.y, ra.z, ra.w, rb.x, rb.y, rb.z, rb.w};
        unsigned u[8]; float wgt[8];
#pragma unroll
        for (int j = 0; j < 8; ++j) u[j] = h2[(size_t)s[j] * (D / 2) + lane];
#pragma unroll
        for (int j = 0; j < 8; ++j) wgt[j] = rsqrtf((float)degi[s[j]] + 1.0f) * di;
#pragma unroll
        for (int j = 0; j < 8; ++j) acc_edge(acc0, acc1, u[j], wgt[j]);
    }
    int rem = dgc - e;
    if (rem & 4) {
        int4 ra = *(const int4*)&bk[e];
        int s[4] = {ra.x, ra.y, ra.z, ra.w};
        unsigned u[4]; float wgt[4];
#pragma unroll
        for (int j = 0; j < 4; ++j) u[j] = h2[(size_t)s[j] * (D / 2) + lane];
#pragma unroll
        for (int j = 0; j < 4; ++j) wgt[j] = rsqrtf((float)degi[s[j]] + 1.0f) * di;
#pragma unroll
        for (int j = 0; j < 4; ++j) acc_edge(acc0, acc1, u[j], wgt[j]);
        e += 4;
    }
    if (rem & 2) {
        int s0 = bk[e], s1 = bk[e + 1];
        unsigned u0 = h2[(size_t)s0 * (D / 2) + lane];
        unsigned u1 = h2[(size_t)s1 * (D / 2) + lane];
        float w0 = rsqrtf((float)degi[s0] + 1.0f) * di;
        float w1 = rsqrtf((float)degi[s1] + 1.0f) * di;
        acc_edge(acc0, acc1, u0, w0);
        acc_edge(acc0, acc1, u1, w1);
        e += 2;
    }
    if (rem & 1) {
        int s0 = bk[e];
        unsigned u0 = h2[(size_t)s0 * (D / 2) + lane];
        float w0 = rsqrtf((float)degi[s0] + 1.0f) * di;
        acc_edge(acc0, acc1, u0, w0);
    }

    float2 bb = *(const float2*)&b[lane * 2];
    float v0 = acc0 + bb.x;
    float v1 = acc1 + bb.y;
    float s = v0 + v1;
    float q = v0 * v0 + v1 * v1;
#pragma unroll
    for (int off = 32; off; off >>= 1) {
        s += __shfl_xor(s, off);
        q += __shfl_xor(q, off);
    }
    float mean = s * (1.0f / 128.0f);
    float var  = q * (1.0f / 128.0f) - mean * mean;
    float rstd = rsqrtf(var + LN_EPS);
    float2 gg = *(const float2*)&g[lane * 2];
    float2 eb = *(const float2*)&be[lane * 2];
    float y0 = (v0 - mean) * rstd * gg.x + eb.x;
    float y1 = (v1 - mean) * rstd * gg.y + eb.y;
    *(float2*)&out[(size_t)row * D + lane * 2] = make_float2(fmaxf(y0, 0.0f), fmaxf(y1, 0.0f));
}

extern "C" void kernel_launch(void* const* d_in, const int* in_sizes, int n_in,
                              void* d_out, int out_size, void* d_ws, size_t ws_size,
                              hipStream_t stream) {
    const float* x  = (const float*)d_in[0];
    const int*   ei = (const int*)d_in[1];
    const float* W  = (const float*)d_in[2];
    const float* b  = (const float*)d_in[3];
    const float* g  = (const float*)d_in[4];
    const float* be = (const float*)d_in[5];

    int N = in_sizes[0] / D;
    int E = in_sizes[1] / 2;
    const int* src = ei;
    const int* dst = ei + E;

    float* out = (float*)d_out;

    char* w = (char*)d_ws;
    unsigned* h2    = (unsigned*)w;           w += (size_t)N * (D / 2) * sizeof(unsigned);
    int*      degi  = (int*)w;                w += (size_t)N * sizeof(int);
    _Float16* wtg   = (_Float16*)w;           w += (size_t)D * D * sizeof(_Float16);
    int*      bucket= (int*)w;                w += (size_t)N * BKT * sizeof(int);

    int nbG = (N + 63) / 64;
    int nbB = (E + 255) / 256;

    prep_kernel <<<64,        256, 0, stream>>>(W, wtg, degi, N);
    fused_kernel<<<nbG + nbB, 256, 0, stream>>>(x, wtg, h2, src, dst, degi, bucket,
                                                N, E, nbG);
    gather_ln_kernel<<<(N + 3) / 4, 256, 0, stream>>>(bucket, degi, h2,
                                                      b, g, be, out, N);
}

// Round 7
// 148.141 us; speedup vs baseline: 1.5659x; 1.0658x over previous
//
#include <hip/hip_runtime.h>
#include <hip/hip_fp16.h>
#include <math.h>

#define D 128
#define LN_EPS 1e-5f
#define BIN_SHIFT 7          // 128 dsts per bin
#define BIN_W     128
#define BINCAP    2048       // edge capacity per bin (mean ~1280, +21 sigma)
#define ADJCAP    2560       // adj slots per bin (edges + per-dst ceil-to-4 padding)
#define EPT_BIN   8          // edges per thread in binning pass

typedef _Float16 f16x8 __attribute__((ext_vector_type(8)));
typedef float    f32x4 __attribute__((ext_vector_type(4)));

// ---------------- prep: W^T -> fp16 (once, 32 KB) + zero bin counters ----------------
__global__ void prep_kernel(const float* __restrict__ W, _Float16* __restrict__ wtg,
                            int* __restrict__ binCount, int nbins) {
    int idx = blockIdx.x * 256 + threadIdx.x;     // [0, 16384)
    int k = idx >> 7;
    int n = idx & 127;
    wtg[n * D + k] = (_Float16)W[k * D + n];
    if (idx < nbins) binCount[idx] = 0;
}

// ---------------- fused gemm || edge-binning: one dispatch ----------------
// Blocks [0,nbG): MFMA GEMM h2 = fp16(x @ W) (r0 LDS version, known 22us standalone).
// Blocks [nbG,..): bin edges by dst>>7 via LDS histogram. Global atomics reduced from
// 500K random-address to ~96K on 391 hot counters (theory: random device atomics were
// the ~33us bucket floor; hot-counter serial chains cost ~1us total).
__global__ void fused_kernel(const float* __restrict__ x, const _Float16* __restrict__ wtg,
                             unsigned* __restrict__ h2,
                             const int* __restrict__ src, const int* __restrict__ dst,
                             int* __restrict__ binCount, int* __restrict__ binBuf,
                             int N, int E, int nbG) {
    __shared__ char smem[17408];
    int tid = threadIdx.x;

    if ((int)blockIdx.x >= nbG) {
        // ---- binning branch ----
        int* hist = (int*)smem;        // [<=400]
        int* base = hist + 400;        // [<=400]
        int nbins = (N + BIN_W - 1) >> BIN_SHIFT;
        int e0 = (blockIdx.x - nbG) * (256 * EPT_BIN);
        for (int i = tid; i < nbins; i += 256) hist[i] = 0;
        __syncthreads();
        int dv[EPT_BIN], ls[EPT_BIN];
#pragma unroll
        for (int j = 0; j < EPT_BIN; ++j) {
            int e = e0 + tid + j * 256;
            dv[j] = (e < E) ? dst[e] : -1;
        }
#pragma unroll
        for (int j = 0; j < EPT_BIN; ++j)
            if (dv[j] >= 0) ls[j] = atomicAdd(&hist[dv[j] >> BIN_SHIFT], 1);
        __syncthreads();
        for (int i = tid; i < nbins; i += 256)
            base[i] = hist[i] ? atomicAdd(&binCount[i], hist[i]) : 0;
        __syncthreads();
#pragma unroll
        for (int j = 0; j < EPT_BIN; ++j) {
            if (dv[j] >= 0) {
                int e    = e0 + tid + j * 256;
                int bin  = dv[j] >> BIN_SHIFT;
                int slot = base[bin] + ls[j];
                if (slot < BINCAP)
                    binBuf[bin * BINCAP + slot] = ((dv[j] & (BIN_W - 1)) << 16) | src[e];
            }
        }
        return;
    }

    // ---- gemm branch (r0 LDS version) ----
    _Float16 (*xs)[136] = (_Float16(*)[136])smem;
    int row0 = blockIdx.x * 64;
#pragma unroll
    for (int i = 0; i < 8; ++i) {
        int idx = i * 256 + tid;
        int r   = idx >> 5;
        int c4  = idx & 31;
        float4 v = make_float4(0.f, 0.f, 0.f, 0.f);
        if (row0 + r < N) v = *(const float4*)&x[(size_t)(row0 + r) * D + c4 * 4];
        __half2 lo = __floats2half2_rn(v.x, v.y);
        __half2 hi = __floats2half2_rn(v.z, v.w);
        *(__half2*)&xs[r][c4 * 4]     = lo;
        *(__half2*)&xs[r][c4 * 4 + 2] = hi;
    }
    __syncthreads();

    int l     = tid & 63;
    int mtile = tid >> 6;
    int mn    = l & 15;
    int kq    = (l >> 4) * 8;
    f32x4 acc[8];
#pragma unroll
    for (int nt = 0; nt < 8; ++nt) acc[nt] = (f32x4){0.f, 0.f, 0.f, 0.f};

#pragma unroll
    for (int ks = 0; ks < 4; ++ks) {
        int kb = ks * 32 + kq;
        f16x8 a = *(f16x8*)&xs[mtile * 16 + mn][kb];
#pragma unroll
        for (int nt = 0; nt < 8; ++nt) {
            f16x8 bf = *(const f16x8*)&wtg[(nt * 16 + mn) * D + kb];
            acc[nt] = __builtin_amdgcn_mfma_f32_16x16x32_f16(a, bf, acc[nt], 0, 0, 0);
        }
    }

    int quad = l >> 4;
#pragma unroll
    for (int nt = 0; nt < 8; ++nt) {
#pragma unroll
        for (int rg = 0; rg < 4; ++rg) {
            float v  = acc[nt][rg];
            float pv = __shfl_xor(v, 1);
            if (!(l & 1)) {
                int row = row0 + mtile * 16 + quad * 4 + rg;
                if (row < N) {
                    __half2 p = __floats2half2_rn(v, pv);
                    h2[(size_t)row * (D / 2) + nt * 8 + (mn >> 1)] = *(unsigned*)&p;
                }
            }
        }
    }
}

// ---------------- CSR build: one block per bin, all LDS atomics ----------------
__global__ void csr_kernel(const int* __restrict__ binBuf, const int* __restrict__ binCount,
                           int* __restrict__ rowStart, int* __restrict__ degi,
                           int* __restrict__ adj, int N) {
    __shared__ int deg2[BIN_W], start[BIN_W], cur[BIN_W];
    int b   = blockIdx.x;
    int tid = threadIdx.x;
    int cnt = binCount[b];
    if (cnt > BINCAP) cnt = BINCAP;
    if (tid < BIN_W) deg2[tid] = 0;
    __syncthreads();
    const int* bb = binBuf + (size_t)b * BINCAP;
    for (int i = tid; i < cnt; i += 256) atomicAdd(&deg2[bb[i] >> 16], 1);
    __syncthreads();
    if (tid == 0) {
        int off = 0;
        for (int d = 0; d < BIN_W; ++d) { start[d] = off; off += (deg2[d] + 3) & ~3; }
    }
    __syncthreads();
    if (tid < BIN_W) {
        int dg = b * BIN_W + tid;
        if (dg < N) {
            degi[dg]     = deg2[tid];
            rowStart[dg] = b * ADJCAP + start[tid];
        }
        cur[tid] = 0;
    }
    __syncthreads();
    int* ab = adj + (size_t)b * ADJCAP;
    for (int i = tid; i < cnt; i += 256) {
        int v    = bb[i];
        int ld   = v >> 16;
        int slot = atomicAdd(&cur[ld], 1);
        ab[start[ld] + slot] = v & 0xFFFF;
    }
}

// ---------------- fused pull-aggregate + bias + LayerNorm + ReLU ----------------
// Dense CSR rows (4-aligned rowStart), exact degrees. Same 8/4/2/1 batch structure.
__device__ __forceinline__ void acc_edge(float& a0, float& a1, unsigned u, float w) {
    __half2 hv = *(__half2*)&u;
    a0 = fmaf(__low2float(hv),  w, a0);
    a1 = fmaf(__high2float(hv), w, a1);
}

__global__ void gather_ln_kernel(const int* __restrict__ rowStart, const int* __restrict__ degi,
                                 const int* __restrict__ adj,
                                 const unsigned* __restrict__ h2, const float* __restrict__ b,
                                 const float* __restrict__ g, const float* __restrict__ be,
                                 float* __restrict__ out, int N) {
    int row  = blockIdx.x * 4 + (threadIdx.x >> 6);
    int lane = threadIdx.x & 63;
    if (row >= N) return;
    int dg   = degi[row];
    int dgc  = dg;
    float di = rsqrtf((float)dg + 1.0f);
    float sw = di * di;
    unsigned su = h2[(size_t)row * (D / 2) + lane];        // self-loop
    float acc0 = 0.f, acc1 = 0.f;
    acc_edge(acc0, acc1, su, sw);
    const int* bk = adj + rowStart[row];

    int e = 0;
    for (; e + 8 <= dgc; e += 8) {
        int4 ra = *(const int4*)&bk[e];
        int4 rb = *(const int4*)&bk[e + 4];
        int s[8] = {ra.x, ra.y, ra.z, ra.w, rb.x, rb.y, rb.z, rb.w};
        unsigned u[8]; float wgt[8];
#pragma unroll
        for (int j = 0; j < 8; ++j) u[j] = h2[(size_t)s[j] * (D / 2) + lane];
#pragma unroll
        for (int j = 0; j < 8; ++j) wgt[j] = rsqrtf((float)degi[s[j]] + 1.0f) * di;
#pragma unroll
        for (int j = 0; j < 8; ++j) acc_edge(acc0, acc1, u[j], wgt[j]);
    }
    int rem = dgc - e;
    if (rem & 4) {
        int4 ra = *(const int4*)&bk[e];
        int s[4] = {ra.x, ra.y, ra.z, ra.w};
        unsigned u[4]; float wgt[4];
#pragma unroll
        for (int j = 0; j < 4; ++j) u[j] = h2[(size_t)s[j] * (D / 2) + lane];
#pragma unroll
        for (int j = 0; j < 4; ++j) wgt[j] = rsqrtf((float)degi[s[j]] + 1.0f) * di;
#pragma unroll
        for (int j = 0; j < 4; ++j) acc_edge(acc0, acc1, u[j], wgt[j]);
        e += 4;
    }
    if (rem & 2) {
        int s0 = bk[e], s1 = bk[e + 1];
        unsigned u0 = h2[(size_t)s0 * (D / 2) + lane];
        unsigned u1 = h2[(size_t)s1 * (D / 2) + lane];
        float w0 = rsqrtf((float)degi[s0] + 1.0f) * di;
        float w1 = rsqrtf((float)degi[s1] + 1.0f) * di;
        acc_edge(acc0, acc1, u0, w0);
        acc_edge(acc0, acc1, u1, w1);
        e += 2;
    }
    if (rem & 1) {
        int s0 = bk[e];
        unsigned u0 = h2[(size_t)s0 * (D / 2) + lane];
        float w0 = rsqrtf((float)degi[s0] + 1.0f) * di;
        acc_edge(acc0, acc1, u0, w0);
    }

    float2 bb = *(const float2*)&b[lane * 2];
    float v0 = acc0 + bb.x;
    float v1 = acc1 + bb.y;
    float s = v0 + v1;
    float q = v0 * v0 + v1 * v1;
#pragma unroll
    for (int off = 32; off; off >>= 1) {
        s += __shfl_xor(s, off);
        q += __shfl_xor(q, off);
    }
    float mean = s * (1.0f / 128.0f);
    float var  = q * (1.0f / 128.0f) - mean * mean;
    float rstd = rsqrtf(var + LN_EPS);
    float2 gg = *(const float2*)&g[lane * 2];
    float2 eb = *(const float2*)&be[lane * 2];
    float y0 = (v0 - mean) * rstd * gg.x + eb.x;
    float y1 = (v1 - mean) * rstd * gg.y + eb.y;
    *(float2*)&out[(size_t)row * D + lane * 2] = make_float2(fmaxf(y0, 0.0f), fmaxf(y1, 0.0f));
}

extern "C" void kernel_launch(void* const* d_in, const int* in_sizes, int n_in,
                              void* d_out, int out_size, void* d_ws, size_t ws_size,
                              hipStream_t stream) {
    const float* x  = (const float*)d_in[0];
    const int*   ei = (const int*)d_in[1];
    const float* W  = (const float*)d_in[2];
    const float* b  = (const float*)d_in[3];
    const float* g  = (const float*)d_in[4];
    const float* be = (const float*)d_in[5];

    int N = in_sizes[0] / D;
    int E = in_sizes[1] / 2;
    const int* src = ei;
    const int* dst = ei + E;

    float* out = (float*)d_out;

    int nbins = (N + BIN_W - 1) / BIN_W;

    char* w = (char*)d_ws;
    unsigned* h2      = (unsigned*)w;   w += (size_t)N * (D / 2) * sizeof(unsigned);
    _Float16* wtg     = (_Float16*)w;   w += (size_t)D * D * sizeof(_Float16);
    int*      binCount= (int*)w;        w += (size_t)1024 * sizeof(int);
    int*      binBuf  = (int*)w;        w += (size_t)nbins * BINCAP * sizeof(int);
    int*      adj     = (int*)w;        w += (size_t)nbins * ADJCAP * sizeof(int);
    int*      rowStart= (int*)w;        w += (size_t)N * sizeof(int);
    int*      degi    = (int*)w;        w += (size_t)N * sizeof(int);

    int nbG = (N + 63) / 64;
    int nbB = (E + 256 * EPT_BIN - 1) / (256 * EPT_BIN);

    prep_kernel <<<64,        256, 0, stream>>>(W, wtg, binCount, nbins);
    fused_kernel<<<nbG + nbB, 256, 0, stream>>>(x, wtg, h2, src, dst, binCount, binBuf,
                                                N, E, nbG);
    csr_kernel  <<<nbins,     256, 0, stream>>>(binBuf, binCount, rowStart, degi, adj, N);
    gather_ln_kernel<<<(N + 3) / 4, 256, 0, stream>>>(rowStart, degi, adj, h2,
                                                      b, g, be, out, N);
}